// Round 15
// baseline (169.212 us; speedup 1.0000x reference)
//
#include <hip/hip_runtime.h>

#define NN 50000
#define NE 800000
#define DD 64
#define BS 100          // nodes per bucket
#define NB 500          // buckets (NB*BS == NN)
#define ECAP 2048       // edge slots per bucket (mean 1600, sigma 40)
#define CHUNK 3200      // edges per partition block
#define NPB 250         // partition blocks (NPB*CHUNK == NE)
#define EPT (ECAP / 256)  // 8 edges per thread in bucket_sort
#define NGRID (NN / 16)   // 3125 blocks per layer copy
#define AMP 8             // layer-0 amplification (instrumentation)

// ---------------- helpers ----------------

__device__ __forceinline__ unsigned bf16_rnd(float f) {
    unsigned u = __float_as_uint(f);
    return u + 0x7FFFu + ((u >> 16) & 1u);     // RNE, take high 16
}
__device__ __forceinline__ unsigned pack2(float lo, float hi) {
    return (bf16_rnd(lo) >> 16) | (bf16_rnd(hi) & 0xFFFF0000u);
}
__device__ __forceinline__ float blo(unsigned u) { return __uint_as_float(u << 16); }
__device__ __forceinline__ float bhi(unsigned u) { return __uint_as_float(u & 0xFFFF0000u); }

// h (f32, NN*DD) -> packed bf16; block 0 also zeroes gpos (fused, saves a launch).
__global__ __launch_bounds__(256) void f32_to_bf16_zero_kernel(
        const float4* __restrict__ in4, uint4* __restrict__ out4,
        int* __restrict__ gpos) {
    if (blockIdx.x == 0) {
        for (int j = threadIdx.x; j < NB; j += 256) gpos[j] = 0;
    }
    int i = blockIdx.x * blockDim.x + threadIdx.x;
    if (i >= NN * DD / 8) return;
    float4 a = in4[2 * i], b = in4[2 * i + 1];
    uint4 o;
    o.x = pack2(a.x, a.y); o.y = pack2(a.z, a.w);
    o.z = pack2(b.x, b.y); o.w = pack2(b.z, b.w);
    out4[i] = o;
}

// ---------------- edge partition by dst bucket, 1024-thread blocks ---------
__global__ __launch_bounds__(1024) void partition_kernel(
        const int* __restrict__ src, const int* __restrict__ dst,
        const float* __restrict__ ew,
        int* __restrict__ gpos, uint2* __restrict__ ebuf) {
    __shared__ int hist[NB];
    __shared__ int base[NB];
    int t = threadIdx.x;
    int c0 = blockIdx.x * CHUNK;

    for (int j = t; j < NB; j += 1024) hist[j] = 0;
    __syncthreads();

    short rank[4];
    int   dcache[4];
    #pragma unroll
    for (int i = 0; i < 4; ++i) {
        int o = i * 1024 + t;
        if (o < CHUNK) {
            int d = dst[c0 + o];
            dcache[i] = d;
            rank[i] = (short)atomicAdd(&hist[d / BS], 1);
        }
    }
    __syncthreads();

    for (int j = t; j < NB; j += 1024) {
        int c = hist[j];
        base[j] = c ? atomicAdd(&gpos[j], c) : 0;
    }
    __syncthreads();

    #pragma unroll
    for (int i = 0; i < 4; ++i) {
        int o = i * 1024 + t;
        if (o < CHUNK) {
            int e = c0 + o;
            int d = dcache[i];
            int bkt = d / BS;
            int dl = d - bkt * BS;
            int pos = base[bkt] + (int)rank[i];
            if (pos < ECAP) {
                ebuf[(size_t)bkt * ECAP + pos] =
                    make_uint2((unsigned)src[e] | ((unsigned)dl << 16),
                               __float_as_uint(ew[e]));
            }
        }
    }
}

// ---------------- per-bucket counting sort + within-bucket degree sort -----
__global__ __launch_bounds__(256) void bucket_sort_kernel(
        const uint2* __restrict__ ebuf, const int* __restrict__ gpos,
        unsigned* __restrict__ sorted, int4* __restrict__ nodespan) {
    __shared__ int hist[BS];
    __shared__ int sc[BS];
    __shared__ int dh[128];
    __shared__ int dsc[128];
    int t = threadIdx.x;
    int b = blockIdx.x;
    int cnt = min(gpos[b], ECAP);
    const uint2* slab = ebuf + (size_t)b * ECAP;

    if (t < BS) hist[t] = 0;
    if (t < 128) dh[t] = 0;
    __syncthreads();

    unsigned pay[EPT];
    int dl[EPT], rk[EPT];
    #pragma unroll
    for (int i = 0; i < EPT; ++i) {
        int o = i * 256 + t;
        if (o < cnt) {
            uint2 q = slab[o];
            dl[i]  = (int)(q.x >> 16);
            pay[i] = (q.x & 0xFFFFu) | (bf16_rnd(__uint_as_float(q.y)) & 0xFFFF0000u);
            rk[i]  = atomicAdd(&hist[dl[i]], 1);
        }
    }
    __syncthreads();

    if (t < BS) sc[t] = hist[t];
    __syncthreads();
    #pragma unroll
    for (int off = 1; off < BS; off <<= 1) {
        int v = (t < BS && t >= off) ? sc[t - off] : 0;
        __syncthreads();
        if (t < BS) sc[t] += v;
        __syncthreads();
    }

    unsigned* oslab = sorted + (size_t)b * ECAP;
    #pragma unroll
    for (int i = 0; i < EPT; ++i) {
        int o = i * 256 + t;
        if (o < cnt) oslab[sc[dl[i]] - hist[dl[i]] + rk[i]] = pay[i];
    }

    // ---- degree sort of the BS nodes ----
    if (t < BS) atomicAdd(&dh[min(hist[t], 127)], 1);
    __syncthreads();
    if (t < 128) dsc[t] = dh[t];
    __syncthreads();
    #pragma unroll
    for (int off = 1; off < 128; off <<= 1) {
        int v = (t < 128 && t >= off) ? dsc[t - off] : 0;
        __syncthreads();
        if (t < 128) dsc[t] += v;
        __syncthreads();
    }
    if (t < 128) dh[t] = dsc[t] - dh[t];
    __syncthreads();
    if (t < BS) {
        int d = min(hist[t], 127);
        int p = atomicAdd(&dh[d], 1);
        nodespan[b * BS + p] =
            make_int4(b * ECAP + sc[t] - hist[t], hist[t], b * BS + t, 0);
    }
}

// ---------------- fused gather(bf16) + dense + relu ------------------------
// ncopy>1: blocks beyond the first NGRID redo the same work into outp2
// (identical values, benign) purely to amplify the dispatch for profiling.
template<bool WRITE_BF16>
__global__ __launch_bounds__(256) void gcn_layer_kernel(
        const uint2* __restrict__ hb,
        const unsigned* __restrict__ sorted,
        const int4* __restrict__ nodespan,    // {start, deg, node, 0}
        const float* __restrict__ W,
        const float* __restrict__ b,
        void* __restrict__ outp,
        void* __restrict__ outp2) {
    __shared__ float4 Wl[DD * 16];
    __shared__ float Arow[16][68];
    int t = threadIdx.x;

    const float4* W4 = reinterpret_cast<const float4*>(W);
    #pragma unroll
    for (int i = 0; i < 4; ++i) Wl[t + 256 * i] = W4[t + 256 * i];

    int copy = blockIdx.x / NGRID;
    int vb   = blockIdx.x - copy * NGRID;
    void* op = (copy == 0) ? outp : outp2;

    int g = t >> 4;
    int lane = t & 15;
    int v = vb * 16 + g;

    int4 sp = nodespan[v];
    const unsigned* row = sorted + sp.x;
    int deg = sp.y;
    int node = sp.z;

    float4 a0 = make_float4(0.f, 0.f, 0.f, 0.f);
    float4 a1 = make_float4(0.f, 0.f, 0.f, 0.f);
    float4 a2 = make_float4(0.f, 0.f, 0.f, 0.f);
    float4 a3 = make_float4(0.f, 0.f, 0.f, 0.f);
    for (int k0 = 0; k0 < deg; k0 += 16) {
        int kk = k0 + lane;
        unsigned q = (kk < deg) ? row[kk] : 0u;
        int lim = min(16, deg - k0);
        int j = 0;
        for (; j + 4 <= lim; j += 4) {
            unsigned q0 = (unsigned)__shfl((int)q, j + 0, 16);
            unsigned q1 = (unsigned)__shfl((int)q, j + 1, 16);
            unsigned q2 = (unsigned)__shfl((int)q, j + 2, 16);
            unsigned q3 = (unsigned)__shfl((int)q, j + 3, 16);
            uint2 r0 = hb[(size_t)(q0 & 0xFFFFu) * 16 + lane];
            uint2 r1 = hb[(size_t)(q1 & 0xFFFFu) * 16 + lane];
            uint2 r2 = hb[(size_t)(q2 & 0xFFFFu) * 16 + lane];
            uint2 r3 = hb[(size_t)(q3 & 0xFFFFu) * 16 + lane];
            float w0 = bhi(q0), w1 = bhi(q1), w2 = bhi(q2), w3 = bhi(q3);
            a0.x += w0 * blo(r0.x); a0.y += w0 * bhi(r0.x);
            a0.z += w0 * blo(r0.y); a0.w += w0 * bhi(r0.y);
            a1.x += w1 * blo(r1.x); a1.y += w1 * bhi(r1.x);
            a1.z += w1 * blo(r1.y); a1.w += w1 * bhi(r1.y);
            a2.x += w2 * blo(r2.x); a2.y += w2 * bhi(r2.x);
            a2.z += w2 * blo(r2.y); a2.w += w2 * bhi(r2.y);
            a3.x += w3 * blo(r3.x); a3.y += w3 * bhi(r3.x);
            a3.z += w3 * blo(r3.y); a3.w += w3 * bhi(r3.y);
        }
        for (; j < lim; ++j) {
            unsigned q0 = (unsigned)__shfl((int)q, j, 16);
            float w0 = bhi(q0);
            uint2 r0 = hb[(size_t)(q0 & 0xFFFFu) * 16 + lane];
            a0.x += w0 * blo(r0.x); a0.y += w0 * bhi(r0.x);
            a0.z += w0 * blo(r0.y); a0.w += w0 * bhi(r0.y);
        }
    }
    a0.x += a1.x + a2.x + a3.x;
    a0.y += a1.y + a2.y + a3.y;
    a0.z += a1.z + a2.z + a3.z;
    a0.w += a1.w + a2.w + a3.w;

    Arow[g][lane * 4 + 0] = a0.x;
    Arow[g][lane * 4 + 1] = a0.y;
    Arow[g][lane * 4 + 2] = a0.z;
    Arow[g][lane * 4 + 3] = a0.w;
    __syncthreads();

    float4 o = reinterpret_cast<const float4*>(b)[lane];
    #pragma unroll
    for (int kk = 0; kk < DD; ++kk) {
        float a = Arow[g][kk];
        float4 wv = Wl[kk * 16 + lane];
        o.x += a * wv.x;
        o.y += a * wv.y;
        o.z += a * wv.z;
        o.w += a * wv.w;
    }
    o.x = fmaxf(o.x, 0.f);
    o.y = fmaxf(o.y, 0.f);
    o.z = fmaxf(o.z, 0.f);
    o.w = fmaxf(o.w, 0.f);

    if (WRITE_BF16) {
        reinterpret_cast<uint2*>(op)[(size_t)node * 16 + lane] =
            make_uint2(pack2(o.x, o.y), pack2(o.z, o.w));
    } else {
        reinterpret_cast<float4*>(op)[(size_t)node * 16 + lane] = o;
    }
}

extern "C" void kernel_launch(void* const* d_in, const int* in_sizes, int n_in,
                              void* d_out, int out_size, void* d_ws, size_t ws_size,
                              hipStream_t stream) {
    const float* h   = (const float*)d_in[0];
    const float* Ws  = (const float*)d_in[1];   // [2][64][64]
    const float* bs  = (const float*)d_in[2];   // [2][64]
    const float* ew  = (const float*)d_in[3];
    const int*   src = (const int*)d_in[4];
    const int*   dst = (const int*)d_in[5];
    float* out = (float*)d_out;
    char* ws = (char*)d_ws;

    // ws layout (~31 MB):
    //   gpos:     [0, 2 KB)
    //   ebuf:     [64 KB, 8.06 MB)      NB*ECAP uint2  [dead after sort]
    //   h1:       [1 MB, 7.4 MB)        aliases dead ebuf region
    //   sorted:   [9 MB, 13 MB)         NB*ECAP uint
    //   nodespan: [13.25 MB, 14.05 MB)  NN int4
    //   h_bf:     [14.5 MB, 20.9 MB)    NN*DD bf16
    //   h2:       [24 MB, 30.4 MB)      scratch for amplified copies
    int*      gpos     = (int*)(ws);
    uint2*    ebuf     = (uint2*)(ws + 64 * 1024);
    void*     h1       = (void*)(ws + 1u * 1024 * 1024);
    unsigned* sorted   = (unsigned*)(ws + 9u * 1024 * 1024);
    int4*     nodespan = (int4*)(ws + 13u * 1024 * 1024 + 256 * 1024);
    uint2*    h_bf     = (uint2*)(ws + 14u * 1024 * 1024 + 512 * 1024);
    void*     h2       = (void*)(ws + 24u * 1024 * 1024);

    dim3 blk(256);

    f32_to_bf16_zero_kernel<<<(NN * DD / 8 + 255) / 256, blk, 0, stream>>>(
        (const float4*)h, (uint4*)h_bf, gpos);
    partition_kernel<<<NPB, dim3(1024), 0, stream>>>(src, dst, ew, gpos, ebuf);
    bucket_sort_kernel<<<NB, blk, 0, stream>>>(ebuf, gpos, sorted, nodespan);

    // Layer 0, AMPLIFIED 8x for profiling: copy 0 -> h1 (real), copies 1-7 -> h2.
    gcn_layer_kernel<true><<<AMP * NGRID, blk, 0, stream>>>(
        (const uint2*)h_bf, sorted, nodespan, Ws, bs, h1, h2);
    // Layer 1: h1 -> out (f32)
    gcn_layer_kernel<false><<<NGRID, blk, 0, stream>>>(
        (const uint2*)h1, sorted, nodespan, Ws + DD * DD, bs + DD, (void*)out, h2);
}

// Round 16
// 89.247 us; speedup vs baseline: 1.8960x; 1.8960x over previous
//
#include <hip/hip_runtime.h>

#define NN 50000
#define NE 800000
#define DD 64
#define BS 100          // nodes per bucket
#define NB 500          // buckets (NB*BS == NN)
#define ECAP 2048       // edge slots per bucket (mean 1600, sigma 40)
#define CHUNK 3200      // edges per partition block
#define NPB 250         // partition blocks (NPB*CHUNK == NE)
#define EPT (ECAP / 256)  // 8 edges per thread in bucket_sort
#define NGRID (NN / 16)   // 3125 blocks per layer

// ---------------- helpers ----------------

__device__ __forceinline__ unsigned bf16_rnd(float f) {
    unsigned u = __float_as_uint(f);
    return u + 0x7FFFu + ((u >> 16) & 1u);     // RNE, take high 16
}
__device__ __forceinline__ float bhi(unsigned u) { return __uint_as_float(u & 0xFFFF0000u); }

__global__ void zero_gpos_kernel(int* __restrict__ p) {
    int i = threadIdx.x;
    if (i < NB) p[i] = 0;
    if (i + 256 < NB) p[i + 256] = 0;
}

// ---------------- edge partition by dst bucket, 1024-thread blocks ---------
__global__ __launch_bounds__(1024) void partition_kernel(
        const int* __restrict__ src, const int* __restrict__ dst,
        const float* __restrict__ ew,
        int* __restrict__ gpos, uint2* __restrict__ ebuf) {
    __shared__ int hist[NB];
    __shared__ int base[NB];
    int t = threadIdx.x;
    int c0 = blockIdx.x * CHUNK;

    for (int j = t; j < NB; j += 1024) hist[j] = 0;
    __syncthreads();

    short rank[4];
    int   dcache[4];
    #pragma unroll
    for (int i = 0; i < 4; ++i) {
        int o = i * 1024 + t;
        if (o < CHUNK) {
            int d = dst[c0 + o];
            dcache[i] = d;
            rank[i] = (short)atomicAdd(&hist[d / BS], 1);
        }
    }
    __syncthreads();

    for (int j = t; j < NB; j += 1024) {
        int c = hist[j];
        base[j] = c ? atomicAdd(&gpos[j], c) : 0;
    }
    __syncthreads();

    #pragma unroll
    for (int i = 0; i < 4; ++i) {
        int o = i * 1024 + t;
        if (o < CHUNK) {
            int e = c0 + o;
            int d = dcache[i];
            int bkt = d / BS;
            int dl = d - bkt * BS;
            int pos = base[bkt] + (int)rank[i];
            if (pos < ECAP) {
                ebuf[(size_t)bkt * ECAP + pos] =
                    make_uint2((unsigned)src[e] | ((unsigned)dl << 16),
                               __float_as_uint(ew[e]));
            }
        }
    }
}

// ---------------- per-bucket counting sort + within-bucket degree sort -----
__global__ __launch_bounds__(256) void bucket_sort_kernel(
        const uint2* __restrict__ ebuf, const int* __restrict__ gpos,
        unsigned* __restrict__ sorted, int4* __restrict__ nodespan) {
    __shared__ int hist[BS];
    __shared__ int sc[BS];
    __shared__ int dh[128];
    __shared__ int dsc[128];
    int t = threadIdx.x;
    int b = blockIdx.x;
    int cnt = min(gpos[b], ECAP);
    const uint2* slab = ebuf + (size_t)b * ECAP;

    if (t < BS) hist[t] = 0;
    if (t < 128) dh[t] = 0;
    __syncthreads();

    unsigned pay[EPT];
    int dl[EPT], rk[EPT];
    #pragma unroll
    for (int i = 0; i < EPT; ++i) {
        int o = i * 256 + t;
        if (o < cnt) {
            uint2 q = slab[o];
            dl[i]  = (int)(q.x >> 16);
            pay[i] = (q.x & 0xFFFFu) | (bf16_rnd(__uint_as_float(q.y)) & 0xFFFF0000u);
            rk[i]  = atomicAdd(&hist[dl[i]], 1);
        }
    }
    __syncthreads();

    if (t < BS) sc[t] = hist[t];
    __syncthreads();
    #pragma unroll
    for (int off = 1; off < BS; off <<= 1) {
        int v = (t < BS && t >= off) ? sc[t - off] : 0;
        __syncthreads();
        if (t < BS) sc[t] += v;
        __syncthreads();
    }

    unsigned* oslab = sorted + (size_t)b * ECAP;
    #pragma unroll
    for (int i = 0; i < EPT; ++i) {
        int o = i * 256 + t;
        if (o < cnt) oslab[sc[dl[i]] - hist[dl[i]] + rk[i]] = pay[i];
    }

    // ---- degree sort of the BS nodes ----
    if (t < BS) atomicAdd(&dh[min(hist[t], 127)], 1);
    __syncthreads();
    if (t < 128) dsc[t] = dh[t];
    __syncthreads();
    #pragma unroll
    for (int off = 1; off < 128; off <<= 1) {
        int v = (t < 128 && t >= off) ? dsc[t - off] : 0;
        __syncthreads();
        if (t < 128) dsc[t] += v;
        __syncthreads();
    }
    if (t < 128) dh[t] = dsc[t] - dh[t];
    __syncthreads();
    if (t < BS) {
        int d = min(hist[t], 127);
        int p = atomicAdd(&dh[d], 1);
        nodespan[b * BS + p] =
            make_int4(b * ECAP + sc[t] - hist[t], hist[t], b * BS + t, 0);
    }
}

// ---------------- fused gather(f32) + dense + relu -------------------------
// 16 lanes per node slot; lane holds 4 dims as f32 (float4 gather, 256 B/row).
// No unpack VALU work; only the bf16 edge weight is decoded (1 AND per edge).
__global__ __launch_bounds__(256) void gcn_layer_kernel(
        const float4* __restrict__ hf,        // [NN*16] f32 rows
        const unsigned* __restrict__ sorted,
        const int4* __restrict__ nodespan,    // {start, deg, node, 0}
        const float* __restrict__ W,          // [DD][DD] row-major (k, c)
        const float* __restrict__ b,
        float4* __restrict__ outp) {
    __shared__ float4 Wl[DD * 16];            // Wl[k*16+c4] = W[k][4c4..4c4+3]
    __shared__ float Arow[16][68];
    int t = threadIdx.x;

    const float4* W4 = reinterpret_cast<const float4*>(W);
    #pragma unroll
    for (int i = 0; i < 4; ++i) Wl[t + 256 * i] = W4[t + 256 * i];

    int g = t >> 4;
    int lane = t & 15;
    int v = blockIdx.x * 16 + g;

    int4 sp = nodespan[v];
    const unsigned* row = sorted + sp.x;
    int deg = sp.y;
    int node = sp.z;

    float4 a0 = make_float4(0.f, 0.f, 0.f, 0.f);
    float4 a1 = make_float4(0.f, 0.f, 0.f, 0.f);
    float4 a2 = make_float4(0.f, 0.f, 0.f, 0.f);
    float4 a3 = make_float4(0.f, 0.f, 0.f, 0.f);
    for (int k0 = 0; k0 < deg; k0 += 16) {
        int kk = k0 + lane;
        unsigned q = (kk < deg) ? row[kk] : 0u;
        int lim = min(16, deg - k0);
        int j = 0;
        for (; j + 4 <= lim; j += 4) {
            unsigned q0 = (unsigned)__shfl((int)q, j + 0, 16);
            unsigned q1 = (unsigned)__shfl((int)q, j + 1, 16);
            unsigned q2 = (unsigned)__shfl((int)q, j + 2, 16);
            unsigned q3 = (unsigned)__shfl((int)q, j + 3, 16);
            float4 r0 = hf[(size_t)(q0 & 0xFFFFu) * 16 + lane];
            float4 r1 = hf[(size_t)(q1 & 0xFFFFu) * 16 + lane];
            float4 r2 = hf[(size_t)(q2 & 0xFFFFu) * 16 + lane];
            float4 r3 = hf[(size_t)(q3 & 0xFFFFu) * 16 + lane];
            float w0 = bhi(q0), w1 = bhi(q1), w2 = bhi(q2), w3 = bhi(q3);
            a0.x += w0 * r0.x; a0.y += w0 * r0.y;
            a0.z += w0 * r0.z; a0.w += w0 * r0.w;
            a1.x += w1 * r1.x; a1.y += w1 * r1.y;
            a1.z += w1 * r1.z; a1.w += w1 * r1.w;
            a2.x += w2 * r2.x; a2.y += w2 * r2.y;
            a2.z += w2 * r2.z; a2.w += w2 * r2.w;
            a3.x += w3 * r3.x; a3.y += w3 * r3.y;
            a3.z += w3 * r3.z; a3.w += w3 * r3.w;
        }
        for (; j < lim; ++j) {
            unsigned q0 = (unsigned)__shfl((int)q, j, 16);
            float w0 = bhi(q0);
            float4 r0 = hf[(size_t)(q0 & 0xFFFFu) * 16 + lane];
            a0.x += w0 * r0.x; a0.y += w0 * r0.y;
            a0.z += w0 * r0.z; a0.w += w0 * r0.w;
        }
    }
    a0.x += a1.x + a2.x + a3.x;
    a0.y += a1.y + a2.y + a3.y;
    a0.z += a1.z + a2.z + a3.z;
    a0.w += a1.w + a2.w + a3.w;

    Arow[g][lane * 4 + 0] = a0.x;
    Arow[g][lane * 4 + 1] = a0.y;
    Arow[g][lane * 4 + 2] = a0.z;
    Arow[g][lane * 4 + 3] = a0.w;
    __syncthreads();

    float4 o = reinterpret_cast<const float4*>(b)[lane];
    #pragma unroll
    for (int kk = 0; kk < DD; ++kk) {
        float a = Arow[g][kk];
        float4 wv = Wl[kk * 16 + lane];
        o.x += a * wv.x;
        o.y += a * wv.y;
        o.z += a * wv.z;
        o.w += a * wv.w;
    }
    o.x = fmaxf(o.x, 0.f);
    o.y = fmaxf(o.y, 0.f);
    o.z = fmaxf(o.z, 0.f);
    o.w = fmaxf(o.w, 0.f);

    outp[(size_t)node * 16 + lane] = o;
}

extern "C" void kernel_launch(void* const* d_in, const int* in_sizes, int n_in,
                              void* d_out, int out_size, void* d_ws, size_t ws_size,
                              hipStream_t stream) {
    const float* h   = (const float*)d_in[0];
    const float* Ws  = (const float*)d_in[1];   // [2][64][64]
    const float* bs  = (const float*)d_in[2];   // [2][64]
    const float* ew  = (const float*)d_in[3];
    const int*   src = (const int*)d_in[4];
    const int*   dst = (const int*)d_in[5];
    float* out = (float*)d_out;
    char* ws = (char*)d_ws;

    // ws layout:
    //   gpos:     [0, 2 KB)
    //   ebuf:     [64 KB, 8.06 MB)      NB*ECAP uint2  [dead after sort]
    //   sorted:   [9 MB, 13 MB)         NB*ECAP uint
    //   nodespan: [13.25 MB, 14.05 MB)  NN int4
    //   h1:       [24 MB, 36.8 MB)      NN*DD f32
    int*      gpos     = (int*)(ws);
    uint2*    ebuf     = (uint2*)(ws + 64 * 1024);
    unsigned* sorted   = (unsigned*)(ws + 9u * 1024 * 1024);
    int4*     nodespan = (int4*)(ws + 13u * 1024 * 1024 + 256 * 1024);
    float4*   h1       = (float4*)(ws + 24u * 1024 * 1024);

    dim3 blk(256);

    zero_gpos_kernel<<<1, blk, 0, stream>>>(gpos);
    partition_kernel<<<NPB, dim3(1024), 0, stream>>>(src, dst, ew, gpos, ebuf);
    bucket_sort_kernel<<<NB, blk, 0, stream>>>(ebuf, gpos, sorted, nodespan);

    // Layer 0: h (f32 input, direct) -> h1
    gcn_layer_kernel<<<NGRID, blk, 0, stream>>>(
        (const float4*)h, sorted, nodespan, Ws, bs, h1);
    // Layer 1: h1 -> out
    gcn_layer_kernel<<<NGRID, blk, 0, stream>>>(
        (const float4*)h1, sorted, nodespan, Ws + DD * DD, bs + DD, (float4*)out);
}

// Round 17
// 85.795 us; speedup vs baseline: 1.9723x; 1.0402x over previous
//
#include <hip/hip_runtime.h>

#define NN 50000
#define NE 800000
#define DD 64
#define BS 100          // nodes per bucket
#define NB 500          // buckets (NB*BS == NN)
#define ECAP 2048       // edge slots per bucket (mean 1600, sigma 40)
#define CHUNK 3200      // edges per partition block
#define NPB 250         // partition blocks (NPB*CHUNK == NE)
#define EPT (ECAP / 256)  // 8 edges per thread in bucket_sort
#define NGRID ((NN + 31) / 32)   // 1563 blocks per layer

// ---------------- helpers ----------------

__device__ __forceinline__ unsigned bf16_rnd(float f) {
    unsigned u = __float_as_uint(f);
    return u + 0x7FFFu + ((u >> 16) & 1u);     // RNE, take high 16
}
__device__ __forceinline__ unsigned pack2(float lo, float hi) {
    return (bf16_rnd(lo) >> 16) | (bf16_rnd(hi) & 0xFFFF0000u);
}
__device__ __forceinline__ float blo(unsigned u) { return __uint_as_float(u << 16); }
__device__ __forceinline__ float bhi(unsigned u) { return __uint_as_float(u & 0xFFFF0000u); }

// h (f32, NN*DD) -> packed bf16; block 0 also zeroes gpos (fused).
__global__ __launch_bounds__(256) void f32_to_bf16_zero_kernel(
        const float4* __restrict__ in4, uint4* __restrict__ out4,
        int* __restrict__ gpos) {
    if (blockIdx.x == 0) {
        for (int j = threadIdx.x; j < NB; j += 256) gpos[j] = 0;
    }
    int i = blockIdx.x * blockDim.x + threadIdx.x;
    if (i >= NN * DD / 8) return;
    float4 a = in4[2 * i], b = in4[2 * i + 1];
    uint4 o;
    o.x = pack2(a.x, a.y); o.y = pack2(a.z, a.w);
    o.z = pack2(b.x, b.y); o.w = pack2(b.z, b.w);
    out4[i] = o;
}

// ---------------- edge partition by dst bucket, 1024-thread blocks ---------
__global__ __launch_bounds__(1024) void partition_kernel(
        const int* __restrict__ src, const int* __restrict__ dst,
        const float* __restrict__ ew,
        int* __restrict__ gpos, uint2* __restrict__ ebuf) {
    __shared__ int hist[NB];
    __shared__ int base[NB];
    int t = threadIdx.x;
    int c0 = blockIdx.x * CHUNK;

    for (int j = t; j < NB; j += 1024) hist[j] = 0;
    __syncthreads();

    short rank[4];
    int   dcache[4];
    #pragma unroll
    for (int i = 0; i < 4; ++i) {
        int o = i * 1024 + t;
        if (o < CHUNK) {
            int d = dst[c0 + o];
            dcache[i] = d;
            rank[i] = (short)atomicAdd(&hist[d / BS], 1);
        }
    }
    __syncthreads();

    for (int j = t; j < NB; j += 1024) {
        int c = hist[j];
        base[j] = c ? atomicAdd(&gpos[j], c) : 0;
    }
    __syncthreads();

    #pragma unroll
    for (int i = 0; i < 4; ++i) {
        int o = i * 1024 + t;
        if (o < CHUNK) {
            int e = c0 + o;
            int d = dcache[i];
            int bkt = d / BS;
            int dl = d - bkt * BS;
            int pos = base[bkt] + (int)rank[i];
            if (pos < ECAP) {
                ebuf[(size_t)bkt * ECAP + pos] =
                    make_uint2((unsigned)src[e] | ((unsigned)dl << 16),
                               __float_as_uint(ew[e]));
            }
        }
    }
}

// ---------------- per-bucket counting sort + within-bucket degree sort -----
__global__ __launch_bounds__(256) void bucket_sort_kernel(
        const uint2* __restrict__ ebuf, const int* __restrict__ gpos,
        unsigned* __restrict__ sorted, int4* __restrict__ nodespan) {
    __shared__ int hist[BS];
    __shared__ int sc[BS];
    __shared__ int dh[128];
    __shared__ int dsc[128];
    int t = threadIdx.x;
    int b = blockIdx.x;
    int cnt = min(gpos[b], ECAP);
    const uint2* slab = ebuf + (size_t)b * ECAP;

    if (t < BS) hist[t] = 0;
    if (t < 128) dh[t] = 0;
    __syncthreads();

    unsigned pay[EPT];
    int dl[EPT], rk[EPT];
    #pragma unroll
    for (int i = 0; i < EPT; ++i) {
        int o = i * 256 + t;
        if (o < cnt) {
            uint2 q = slab[o];
            dl[i]  = (int)(q.x >> 16);
            pay[i] = (q.x & 0xFFFFu) | (bf16_rnd(__uint_as_float(q.y)) & 0xFFFF0000u);
            rk[i]  = atomicAdd(&hist[dl[i]], 1);
        }
    }
    __syncthreads();

    if (t < BS) sc[t] = hist[t];
    __syncthreads();
    #pragma unroll
    for (int off = 1; off < BS; off <<= 1) {
        int v = (t < BS && t >= off) ? sc[t - off] : 0;
        __syncthreads();
        if (t < BS) sc[t] += v;
        __syncthreads();
    }

    unsigned* oslab = sorted + (size_t)b * ECAP;
    #pragma unroll
    for (int i = 0; i < EPT; ++i) {
        int o = i * 256 + t;
        if (o < cnt) oslab[sc[dl[i]] - hist[dl[i]] + rk[i]] = pay[i];
    }

    // ---- degree sort of the BS nodes ----
    if (t < BS) atomicAdd(&dh[min(hist[t], 127)], 1);
    __syncthreads();
    if (t < 128) dsc[t] = dh[t];
    __syncthreads();
    #pragma unroll
    for (int off = 1; off < 128; off <<= 1) {
        int v = (t < 128 && t >= off) ? dsc[t - off] : 0;
        __syncthreads();
        if (t < 128) dsc[t] += v;
        __syncthreads();
    }
    if (t < 128) dh[t] = dsc[t] - dh[t];
    __syncthreads();
    if (t < BS) {
        int d = min(hist[t], 127);
        int p = atomicAdd(&dh[d], 1);
        nodespan[b * BS + p] =
            make_int4(b * ECAP + sc[t] - hist[t], hist[t], b * BS + t, 0);
    }
}

// ---------------- fused gather(bf16) + dense + relu ------------------------
// 8 lanes per node slot, uint4 (16 B = 8 dims) per gather: half the loads
// and half the 64-bit address arithmetic of the 16-lane uint2 layout, same
// bytes. 32 nodes per block, degree-sorted slots.
template<bool WRITE_BF16>
__global__ __launch_bounds__(256) void gcn_layer_kernel(
        const uint4* __restrict__ hb,         // [NN*8] bf16-packed rows
        const unsigned* __restrict__ sorted,
        const int4* __restrict__ nodespan,    // {start, deg, node, 0}
        const float* __restrict__ W,          // [DD][DD] row-major (k, c)
        const float* __restrict__ bvec,
        void* __restrict__ outp) {
    __shared__ float4 Wl[DD * 16];            // Wl[k*16+c4] = W[k][4c4..4c4+3]
    __shared__ float Arow[32][65];            // +1 pad
    int t = threadIdx.x;

    const float4* W4 = reinterpret_cast<const float4*>(W);
    #pragma unroll
    for (int i = 0; i < 4; ++i) Wl[t + 256 * i] = W4[t + 256 * i];

    int g = t >> 3;          // node slot 0..31
    int lane = t & 7;        // dims [lane*8, lane*8+8)
    int v = blockIdx.x * 32 + g;

    int4 sp = (v < NN) ? nodespan[v] : make_int4(0, 0, 0, 0);
    const unsigned* row = sorted + sp.x;
    int deg = (v < NN) ? sp.y : 0;

    float accA[8] = {0.f, 0.f, 0.f, 0.f, 0.f, 0.f, 0.f, 0.f};
    float accB[8] = {0.f, 0.f, 0.f, 0.f, 0.f, 0.f, 0.f, 0.f};
    for (int k0 = 0; k0 < deg; k0 += 8) {
        unsigned q = (k0 + lane < deg) ? row[k0 + lane] : 0u;
        int lim = min(8, deg - k0);
        int j = 0;
        for (; j + 2 <= lim; j += 2) {
            unsigned q0 = (unsigned)__shfl((int)q, j, 8);
            unsigned q1 = (unsigned)__shfl((int)q, j + 1, 8);
            float w0 = bhi(q0);
            float w1 = bhi(q1);
            uint4 r0 = hb[(size_t)(q0 & 0xFFFFu) * 8 + lane];
            uint4 r1 = hb[(size_t)(q1 & 0xFFFFu) * 8 + lane];
            accA[0] += w0 * blo(r0.x); accA[1] += w0 * bhi(r0.x);
            accA[2] += w0 * blo(r0.y); accA[3] += w0 * bhi(r0.y);
            accA[4] += w0 * blo(r0.z); accA[5] += w0 * bhi(r0.z);
            accA[6] += w0 * blo(r0.w); accA[7] += w0 * bhi(r0.w);
            accB[0] += w1 * blo(r1.x); accB[1] += w1 * bhi(r1.x);
            accB[2] += w1 * blo(r1.y); accB[3] += w1 * bhi(r1.y);
            accB[4] += w1 * blo(r1.z); accB[5] += w1 * bhi(r1.z);
            accB[6] += w1 * blo(r1.w); accB[7] += w1 * bhi(r1.w);
        }
        if (j < lim) {
            unsigned q0 = (unsigned)__shfl((int)q, j, 8);
            float w0 = bhi(q0);
            uint4 r0 = hb[(size_t)(q0 & 0xFFFFu) * 8 + lane];
            accA[0] += w0 * blo(r0.x); accA[1] += w0 * bhi(r0.x);
            accA[2] += w0 * blo(r0.y); accA[3] += w0 * bhi(r0.y);
            accA[4] += w0 * blo(r0.z); accA[5] += w0 * bhi(r0.z);
            accA[6] += w0 * blo(r0.w); accA[7] += w0 * bhi(r0.w);
        }
    }
    #pragma unroll
    for (int i = 0; i < 8; ++i) Arow[g][lane * 8 + i] = accA[i] + accB[i];
    __syncthreads();

    // dense: c4 = t&15 (col quad), rows rg and rg+16 (rg = t>>4)
    int c4 = t & 15, rg = t >> 4;
    float4 bias = reinterpret_cast<const float4*>(bvec)[c4];
    #pragma unroll
    for (int rr = 0; rr < 2; ++rr) {
        int r = rg + rr * 16;
        int slot = blockIdx.x * 32 + r;
        if (slot >= NN) continue;
        int node = nodespan[slot].z;
        float4 o = bias;
        #pragma unroll
        for (int k = 0; k < DD; ++k) {
            float a = Arow[r][k];
            float4 wv = Wl[k * 16 + c4];
            o.x += a * wv.x; o.y += a * wv.y;
            o.z += a * wv.z; o.w += a * wv.w;
        }
        o.x = fmaxf(o.x, 0.f); o.y = fmaxf(o.y, 0.f);
        o.z = fmaxf(o.z, 0.f); o.w = fmaxf(o.w, 0.f);
        if (WRITE_BF16) {
            reinterpret_cast<uint2*>(outp)[(size_t)node * 16 + c4] =
                make_uint2(pack2(o.x, o.y), pack2(o.z, o.w));
        } else {
            reinterpret_cast<float4*>(outp)[(size_t)node * 16 + c4] = o;
        }
    }
}

extern "C" void kernel_launch(void* const* d_in, const int* in_sizes, int n_in,
                              void* d_out, int out_size, void* d_ws, size_t ws_size,
                              hipStream_t stream) {
    const float* h   = (const float*)d_in[0];
    const float* Ws  = (const float*)d_in[1];   // [2][64][64]
    const float* bs  = (const float*)d_in[2];   // [2][64]
    const float* ew  = (const float*)d_in[3];
    const int*   src = (const int*)d_in[4];
    const int*   dst = (const int*)d_in[5];
    float* out = (float*)d_out;
    char* ws = (char*)d_ws;

    // ws layout (~21 MB):
    //   gpos:     [0, 2 KB)
    //   ebuf:     [64 KB, 8.06 MB)      NB*ECAP uint2  [dead after sort]
    //   h1:       [1 MB, 7.4 MB)        bf16, aliases dead ebuf region
    //   sorted:   [9 MB, 13 MB)         NB*ECAP uint
    //   nodespan: [13.25 MB, 14.05 MB)  NN int4
    //   h_bf:     [14.5 MB, 20.9 MB)    NN*DD bf16
    int*      gpos     = (int*)(ws);
    uint2*    ebuf     = (uint2*)(ws + 64 * 1024);
    void*     h1       = (void*)(ws + 1u * 1024 * 1024);
    unsigned* sorted   = (unsigned*)(ws + 9u * 1024 * 1024);
    int4*     nodespan = (int4*)(ws + 13u * 1024 * 1024 + 256 * 1024);
    uint4*    h_bf     = (uint4*)(ws + 14u * 1024 * 1024 + 512 * 1024);

    dim3 blk(256);

    f32_to_bf16_zero_kernel<<<(NN * DD / 8 + 255) / 256, blk, 0, stream>>>(
        (const float4*)h, (uint4*)h_bf, gpos);
    partition_kernel<<<NPB, dim3(1024), 0, stream>>>(src, dst, ew, gpos, ebuf);
    bucket_sort_kernel<<<NB, blk, 0, stream>>>(ebuf, gpos, sorted, nodespan);

    // Layer 0: h_bf -> h1 (bf16). h1 aliases ebuf, dead after sort.
    gcn_layer_kernel<true><<<NGRID, blk, 0, stream>>>(
        h_bf, sorted, nodespan, Ws, bs, h1);
    // Layer 1: h1 -> out (f32)
    gcn_layer_kernel<false><<<NGRID, blk, 0, stream>>>(
        (const uint4*)h1, sorted, nodespan, Ws + DD * DD, bs + DD, (void*)out);
}

// Round 18
// 64.723 us; speedup vs baseline: 2.6144x; 1.3256x over previous
//
#include <hip/hip_runtime.h>

#define NN 50000
#define NE 800000
#define DD 64
#define BS 100          // nodes per bucket
#define NB 500          // buckets (NB*BS == NN)
#define ECAP 2048       // edge slots per bucket (mean 1600, sigma 40)
#define CHUNK 3200      // edges per partition block
#define NPB 250         // partition blocks (NPB*CHUNK == NE)
#define EPT (ECAP / 256)  // 8 edges per thread in bucket_sort
#define NGRID (NN / 16)   // 3125 blocks per layer

typedef __attribute__((ext_vector_type(8))) short short8;
typedef __attribute__((ext_vector_type(4))) float f32x4;

// ---------------- helpers ----------------

__device__ __forceinline__ unsigned bf16_rnd(float f) {
    unsigned u = __float_as_uint(f);
    return u + 0x7FFFu + ((u >> 16) & 1u);     // RNE, take high 16
}
__device__ __forceinline__ unsigned pack2(float lo, float hi) {
    return (bf16_rnd(lo) >> 16) | (bf16_rnd(hi) & 0xFFFF0000u);
}
__device__ __forceinline__ float blo(unsigned u) { return __uint_as_float(u << 16); }
__device__ __forceinline__ float bhi(unsigned u) { return __uint_as_float(u & 0xFFFF0000u); }

// h (f32) -> packed bf16; block 0 zeroes gpos; blocks 1,2 build W-fragments.
// Wfrag[L][(w*2+s)*64 + l] = uint4 of 8 bf16: element j -> W[32s+8*(l>>4)+j][16w+(l&15)]
__global__ __launch_bounds__(256) void f32_to_bf16_zero_kernel(
        const float4* __restrict__ in4, uint4* __restrict__ out4,
        int* __restrict__ gpos, const float* __restrict__ Ws,
        uint4* __restrict__ wfrag) {
    if (blockIdx.x == 0) {
        for (int j = threadIdx.x; j < NB; j += 256) gpos[j] = 0;
    }
    if (blockIdx.x == 1 || blockIdx.x == 2) {
        int L = blockIdx.x - 1;
        const float* W = Ws + L * DD * DD;
        for (int e = threadIdx.x; e < 512; e += 256) {
            int w = e >> 7;         // col tile 0..3
            int s = (e >> 6) & 1;   // k step 0..1
            int l = e & 63;         // lane
            int col = w * 16 + (l & 15);
            int k0 = 32 * s + 8 * (l >> 4);
            uint4 u;
            unsigned* up = (unsigned*)&u;
            #pragma unroll
            for (int uu = 0; uu < 4; ++uu) {
                float lo = W[(k0 + 2 * uu) * DD + col];
                float hi = W[(k0 + 2 * uu + 1) * DD + col];
                up[uu] = pack2(lo, hi);
            }
            wfrag[L * 512 + e] = u;
        }
    }
    int i = blockIdx.x * blockDim.x + threadIdx.x;
    if (i >= NN * DD / 8) return;
    float4 a = in4[2 * i], b = in4[2 * i + 1];
    uint4 o;
    o.x = pack2(a.x, a.y); o.y = pack2(a.z, a.w);
    o.z = pack2(b.x, b.y); o.w = pack2(b.z, b.w);
    out4[i] = o;
}

// ---------------- edge partition by dst bucket, 1024-thread blocks ---------
__global__ __launch_bounds__(1024) void partition_kernel(
        const int* __restrict__ src, const int* __restrict__ dst,
        const float* __restrict__ ew,
        int* __restrict__ gpos, uint2* __restrict__ ebuf) {
    __shared__ int hist[NB];
    __shared__ int base[NB];
    int t = threadIdx.x;
    int c0 = blockIdx.x * CHUNK;

    for (int j = t; j < NB; j += 1024) hist[j] = 0;
    __syncthreads();

    short rank[4];
    int   dcache[4];
    #pragma unroll
    for (int i = 0; i < 4; ++i) {
        int o = i * 1024 + t;
        if (o < CHUNK) {
            int d = dst[c0 + o];
            dcache[i] = d;
            rank[i] = (short)atomicAdd(&hist[d / BS], 1);
        }
    }
    __syncthreads();

    for (int j = t; j < NB; j += 1024) {
        int c = hist[j];
        base[j] = c ? atomicAdd(&gpos[j], c) : 0;
    }
    __syncthreads();

    #pragma unroll
    for (int i = 0; i < 4; ++i) {
        int o = i * 1024 + t;
        if (o < CHUNK) {
            int e = c0 + o;
            int d = dcache[i];
            int bkt = d / BS;
            int dl = d - bkt * BS;
            int pos = base[bkt] + (int)rank[i];
            if (pos < ECAP) {
                ebuf[(size_t)bkt * ECAP + pos] =
                    make_uint2((unsigned)src[e] | ((unsigned)dl << 16),
                               __float_as_uint(ew[e]));
            }
        }
    }
}

// ---------------- per-bucket counting sort + within-bucket degree sort -----
__global__ __launch_bounds__(256) void bucket_sort_kernel(
        const uint2* __restrict__ ebuf, const int* __restrict__ gpos,
        unsigned* __restrict__ sorted, int4* __restrict__ nodespan) {
    __shared__ int hist[BS];
    __shared__ int sc[BS];
    __shared__ int dh[128];
    __shared__ int dsc[128];
    int t = threadIdx.x;
    int b = blockIdx.x;
    int cnt = min(gpos[b], ECAP);
    const uint2* slab = ebuf + (size_t)b * ECAP;

    if (t < BS) hist[t] = 0;
    if (t < 128) dh[t] = 0;
    __syncthreads();

    unsigned pay[EPT];
    int dl[EPT], rk[EPT];
    #pragma unroll
    for (int i = 0; i < EPT; ++i) {
        int o = i * 256 + t;
        if (o < cnt) {
            uint2 q = slab[o];
            dl[i]  = (int)(q.x >> 16);
            pay[i] = (q.x & 0xFFFFu) | (bf16_rnd(__uint_as_float(q.y)) & 0xFFFF0000u);
            rk[i]  = atomicAdd(&hist[dl[i]], 1);
        }
    }
    __syncthreads();

    if (t < BS) sc[t] = hist[t];
    __syncthreads();
    #pragma unroll
    for (int off = 1; off < BS; off <<= 1) {
        int v = (t < BS && t >= off) ? sc[t - off] : 0;
        __syncthreads();
        if (t < BS) sc[t] += v;
        __syncthreads();
    }

    unsigned* oslab = sorted + (size_t)b * ECAP;
    #pragma unroll
    for (int i = 0; i < EPT; ++i) {
        int o = i * 256 + t;
        if (o < cnt) oslab[sc[dl[i]] - hist[dl[i]] + rk[i]] = pay[i];
    }

    // ---- degree sort of the BS nodes ----
    if (t < BS) atomicAdd(&dh[min(hist[t], 127)], 1);
    __syncthreads();
    if (t < 128) dsc[t] = dh[t];
    __syncthreads();
    #pragma unroll
    for (int off = 1; off < 128; off <<= 1) {
        int v = (t < 128 && t >= off) ? dsc[t - off] : 0;
        __syncthreads();
        if (t < 128) dsc[t] += v;
        __syncthreads();
    }
    if (t < 128) dh[t] = dsc[t] - dh[t];
    __syncthreads();
    if (t < BS) {
        int d = min(hist[t], 127);
        int p = atomicAdd(&dh[d], 1);
        nodespan[b * BS + p] =
            make_int4(b * ECAP + sc[t] - hist[t], hist[t], b * BS + t, 0);
    }
}

// ---------------- fused gather(bf16) + MFMA dense + relu -------------------
// Gather: R14 layout (16 lanes/node, uint2, 4-way unroll). Dense: bf16 agg
// tile [16][64] x W [64][64] on matrix cores; wave w owns cols 16w..16w+15.
// A-frag and Wfrag use the SAME slot->k bijection, so pairing is correct by
// construction; C layout col=lane&15, row=(lane>>4)*4+reg (HW-verified).
template<bool WRITE_BF16>
__global__ __launch_bounds__(256) void gcn_layer_kernel(
        const uint2* __restrict__ hb,         // [NN*16] bf16-packed rows
        const unsigned* __restrict__ sorted,
        const int4* __restrict__ nodespan,    // {start, deg, node, 0}
        const uint4* __restrict__ wfrag,      // [4 waves][2 ksteps][64 lanes]
        const float* __restrict__ bvec,
        void* __restrict__ outp) {
    __shared__ unsigned Abf[16 * 36];         // [row][64 bf16 + pad] (36 uints)
    __shared__ float Dls[16 * 68];
    __shared__ int nid[16];
    int t = threadIdx.x;
    int g = t >> 4;
    int lane = t & 15;
    int v = blockIdx.x * 16 + g;

    int4 sp = nodespan[v];
    if (lane == 0) nid[g] = sp.z;
    const unsigned* row = sorted + sp.x;
    int deg = sp.y;

    float4 a0 = make_float4(0.f, 0.f, 0.f, 0.f);
    float4 a1 = make_float4(0.f, 0.f, 0.f, 0.f);
    float4 a2 = make_float4(0.f, 0.f, 0.f, 0.f);
    float4 a3 = make_float4(0.f, 0.f, 0.f, 0.f);
    for (int k0 = 0; k0 < deg; k0 += 16) {
        int kk = k0 + lane;
        unsigned q = (kk < deg) ? row[kk] : 0u;
        int lim = min(16, deg - k0);
        int j = 0;
        for (; j + 4 <= lim; j += 4) {
            unsigned q0 = (unsigned)__shfl((int)q, j + 0, 16);
            unsigned q1 = (unsigned)__shfl((int)q, j + 1, 16);
            unsigned q2 = (unsigned)__shfl((int)q, j + 2, 16);
            unsigned q3 = (unsigned)__shfl((int)q, j + 3, 16);
            uint2 r0 = hb[(size_t)(q0 & 0xFFFFu) * 16 + lane];
            uint2 r1 = hb[(size_t)(q1 & 0xFFFFu) * 16 + lane];
            uint2 r2 = hb[(size_t)(q2 & 0xFFFFu) * 16 + lane];
            uint2 r3 = hb[(size_t)(q3 & 0xFFFFu) * 16 + lane];
            float w0 = bhi(q0), w1 = bhi(q1), w2 = bhi(q2), w3 = bhi(q3);
            a0.x += w0 * blo(r0.x); a0.y += w0 * bhi(r0.x);
            a0.z += w0 * blo(r0.y); a0.w += w0 * bhi(r0.y);
            a1.x += w1 * blo(r1.x); a1.y += w1 * bhi(r1.x);
            a1.z += w1 * blo(r1.y); a1.w += w1 * bhi(r1.y);
            a2.x += w2 * blo(r2.x); a2.y += w2 * bhi(r2.x);
            a2.z += w2 * blo(r2.y); a2.w += w2 * bhi(r2.y);
            a3.x += w3 * blo(r3.x); a3.y += w3 * bhi(r3.x);
            a3.z += w3 * blo(r3.y); a3.w += w3 * bhi(r3.y);
        }
        for (; j < lim; ++j) {
            unsigned q0 = (unsigned)__shfl((int)q, j, 16);
            float w0 = bhi(q0);
            uint2 r0 = hb[(size_t)(q0 & 0xFFFFu) * 16 + lane];
            a0.x += w0 * blo(r0.x); a0.y += w0 * bhi(r0.x);
            a0.z += w0 * blo(r0.y); a0.w += w0 * bhi(r0.y);
        }
    }
    a0.x += a1.x + a2.x + a3.x;
    a0.y += a1.y + a2.y + a3.y;
    a0.z += a1.z + a2.z + a3.z;
    a0.w += a1.w + a2.w + a3.w;

    // pack agg to bf16: row g, dims 4*lane..4*lane+3 -> uints 2*lane, 2*lane+1
    Abf[g * 36 + 2 * lane]     = pack2(a0.x, a0.y);
    Abf[g * 36 + 2 * lane + 1] = pack2(a0.z, a0.w);
    __syncthreads();

    // ---- MFMA: wave w -> cols 16w..16w+15, K=64 in 2 steps ----
    {
        int w = t >> 6;
        int l = t & 63;
        const uint4* arow = (const uint4*)(&Abf[(l & 15) * 36]);
        uint4 au0 = arow[l >> 4];          // k slots 8*(l>>4)..+7 (step 0)
        uint4 au1 = arow[4 + (l >> 4)];    // same slots, k+32 (step 1)
        uint4 bu0 = wfrag[(w * 2 + 0) * 64 + l];
        uint4 bu1 = wfrag[(w * 2 + 1) * 64 + l];
        f32x4 d = {0.f, 0.f, 0.f, 0.f};
        d = __builtin_amdgcn_mfma_f32_16x16x32_bf16(
                *(const short8*)&au0, *(const short8*)&bu0, d, 0, 0, 0);
        d = __builtin_amdgcn_mfma_f32_16x16x32_bf16(
                *(const short8*)&au1, *(const short8*)&bu1, d, 0, 0, 0);
        #pragma unroll
        for (int r = 0; r < 4; ++r)
            Dls[((l >> 4) * 4 + r) * 68 + w * 16 + (l & 15)] = d[r];
    }
    __syncthreads();

    // ---- epilogue: thread t -> node slot g, cols 4*lane..4*lane+3 ----
    float4 bias = reinterpret_cast<const float4*>(bvec)[lane];
    float4 dv = *reinterpret_cast<const float4*>(&Dls[g * 68 + lane * 4]);
    float4 o;
    o.x = fmaxf(dv.x + bias.x, 0.f);
    o.y = fmaxf(dv.y + bias.y, 0.f);
    o.z = fmaxf(dv.z + bias.z, 0.f);
    o.w = fmaxf(dv.w + bias.w, 0.f);
    int node = nid[g];
    if (WRITE_BF16) {
        reinterpret_cast<uint2*>(outp)[(size_t)node * 16 + lane] =
            make_uint2(pack2(o.x, o.y), pack2(o.z, o.w));
    } else {
        reinterpret_cast<float4*>(outp)[(size_t)node * 16 + lane] = o;
    }
}

extern "C" void kernel_launch(void* const* d_in, const int* in_sizes, int n_in,
                              void* d_out, int out_size, void* d_ws, size_t ws_size,
                              hipStream_t stream) {
    const float* h   = (const float*)d_in[0];
    const float* Ws  = (const float*)d_in[1];   // [2][64][64]
    const float* bs  = (const float*)d_in[2];   // [2][64]
    const float* ew  = (const float*)d_in[3];
    const int*   src = (const int*)d_in[4];
    const int*   dst = (const int*)d_in[5];
    float* out = (float*)d_out;
    char* ws = (char*)d_ws;

    // ws layout (~21 MB):
    //   gpos:     [0, 2 KB)
    //   ebuf:     [64 KB, 8.06 MB)      NB*ECAP uint2  [dead after sort]
    //   h1:       [1 MB, 7.4 MB)        bf16, aliases dead ebuf region
    //   sorted:   [9 MB, 13 MB)         NB*ECAP uint
    //   wfrag:    [13 MB, 13 MB+16 KB)  2 layers x 512 uint4
    //   nodespan: [13.25 MB, 14.05 MB)  NN int4
    //   h_bf:     [14.5 MB, 20.9 MB)    NN*DD bf16
    int*      gpos     = (int*)(ws);
    uint2*    ebuf     = (uint2*)(ws + 64 * 1024);
    void*     h1       = (void*)(ws + 1u * 1024 * 1024);
    unsigned* sorted   = (unsigned*)(ws + 9u * 1024 * 1024);
    uint4*    wfrag    = (uint4*)(ws + 13u * 1024 * 1024);
    int4*     nodespan = (int4*)(ws + 13u * 1024 * 1024 + 256 * 1024);
    uint2*    h_bf     = (uint2*)(ws + 14u * 1024 * 1024 + 512 * 1024);

    dim3 blk(256);

    f32_to_bf16_zero_kernel<<<(NN * DD / 8 + 255) / 256, blk, 0, stream>>>(
        (const float4*)h, (uint4*)h_bf, gpos, Ws, wfrag);
    partition_kernel<<<NPB, dim3(1024), 0, stream>>>(src, dst, ew, gpos, ebuf);
    bucket_sort_kernel<<<NB, blk, 0, stream>>>(ebuf, gpos, sorted, nodespan);

    // Layer 0: h_bf -> h1 (bf16). h1 aliases ebuf, dead after sort.
    gcn_layer_kernel<true><<<NGRID, blk, 0, stream>>>(
        h_bf, sorted, nodespan, wfrag, bs, h1);
    // Layer 1: h1 -> out (f32)
    gcn_layer_kernel<false><<<NGRID, blk, 0, stream>>>(
        (const uint2*)h1, sorted, nodespan, wfrag + 512, bs + DD, (void*)out);
}